// Round 6
// baseline (204.866 us; speedup 1.0000x reference)
//
#include <hip/hip_runtime.h>
#include <math.h>

// Problem constants (B=2, T=2048, E=1024, H=16, S=64)
#define T_SEQ 2048
#define E_DIM 1024
#define NH    16
#define HS    64
#define NB    2
#define M_ROWS 4096

typedef __attribute__((ext_vector_type(8))) short bf16x8;
typedef __attribute__((ext_vector_type(4))) float f32x4;

#define AS1 __attribute__((address_space(1)))
#define AS3 __attribute__((address_space(3)))

#define LOG2E 1.4426950408889634f

__device__ __forceinline__ ushort f2bf(float f) {
    union { float f; unsigned u; } c; c.f = f;
    unsigned r = c.u + 0x7fffu + ((c.u >> 16) & 1u);
    return (ushort)(r >> 16);
}
__device__ __forceinline__ ushort f2bf_trunc(float f) {
    union { float f; unsigned u; } c; c.f = f;
    return (ushort)(c.u >> 16);
}

__device__ __forceinline__ void load_lds16(const ushort* g, ushort* l) {
    // 16B per lane, LDS dest = wave-uniform base + lane*16 (HW behavior)
    __builtin_amdgcn_global_load_lds((const AS1 unsigned int*)g,
                                     (AS3 unsigned int*)l, 16, 0, 0);
}

// ---------------------------------------------------------------------------
// fp32 -> bf16 conversion for x and the four weight matrices.
// ---------------------------------------------------------------------------
__global__ __launch_bounds__(256) void cvt_all(
    const float* __restrict__ x,  const float* __restrict__ Wk,
    const float* __restrict__ Wq, const float* __restrict__ Wv,
    const float* __restrict__ Wu,
    ushort* __restrict__ xb,  ushort* __restrict__ Wkb,
    ushort* __restrict__ Wqb, ushort* __restrict__ Wvb,
    ushort* __restrict__ Wub)
{
    int i4 = blockIdx.x * 256 + threadIdx.x;   // 0 .. 2M-1 (float4 units)
    int region = i4 >> 18;
    const float* src; ushort* dst; int off;
    if      (region < 4)  { src = x;  dst = xb;  off = i4; }
    else if (region == 4) { src = Wk; dst = Wkb; off = i4 - (4 << 18); }
    else if (region == 5) { src = Wq; dst = Wqb; off = i4 - (5 << 18); }
    else if (region == 6) { src = Wv; dst = Wvb; off = i4 - (6 << 18); }
    else                  { src = Wu; dst = Wub; off = i4 - (7 << 18); }
    float4 v = *(const float4*)(src + (size_t)off * 4);
    ushort4 o; o.x = f2bf(v.x); o.y = f2bf(v.y); o.z = f2bf(v.z); o.w = f2bf(v.w);
    *(ushort4*)(dst + (size_t)off * 4) = o;
}

// ---------------------------------------------------------------------------
// bf16 MFMA GEMM core, 128(M)x64(N) tile, BK=32, 4 waves stacked on M
// (wave w owns rows w*32..w*32+31): 2x4 grid of 16x16x32 MFMAs per wave.
// High blocks/CU (12KB LDS) to overlap the per-barrier vmcnt drain at K=1024.
// ---------------------------------------------------------------------------
__device__ __forceinline__ void gemm_core64(
    const ushort* __restrict__ A, const ushort* __restrict__ W,
    int m0, int n0, ushort* As, ushort* Bs, f32x4 acc[2][4])
{
    const int tid  = threadIdx.x;
    const int lane = tid & 63, w = tid >> 6;
    const int quad = lane >> 4, l16 = lane & 15;

    const int rl   = lane >> 2;                       // row-in-chunk 0..15
    const int gsw  = (lane & 3) ^ ((lane >> 3) & 3);  // swizzled global chunk
    const int fsw  = (l16 >> 1) & 3;                  // frag-read xor factor

    const f32x4 zero = {0.f, 0.f, 0.f, 0.f};
#pragma unroll
    for (int mt = 0; mt < 2; ++mt)
#pragma unroll
        for (int nt = 0; nt < 4; ++nt) acc[mt][nt] = zero;

    for (int k0 = 0; k0 < E_DIM; k0 += 32) {
        // A: 8 chunks of 1KB (16 rows x 64B); wave stages chunks w, w+4
#pragma unroll
        for (int i = 0; i < 2; ++i) {
            int c = w + i * 4;
            int row = c * 16 + rl;
            load_lds16(A + (size_t)(m0 + row) * E_DIM + k0 + gsw * 8, As + c * 512);
        }
        // B: 4 chunks; wave stages chunk w
        {
            int row = w * 16 + rl;
            load_lds16(W + (size_t)(n0 + row) * E_DIM + k0 + gsw * 8, Bs + w * 512);
        }
        __syncthreads();
        bf16x8 af[2], bfr[4];
#pragma unroll
        for (int mt = 0; mt < 2; ++mt)
            af[mt] = *(const bf16x8*)(As + (w * 32 + mt * 16 + l16) * 32
                                      + ((quad ^ fsw) * 8));
#pragma unroll
        for (int nt = 0; nt < 4; ++nt)
            bfr[nt] = *(const bf16x8*)(Bs + (nt * 16 + l16) * 32
                                       + ((quad ^ fsw) * 8));
#pragma unroll
        for (int mt = 0; mt < 2; ++mt)
#pragma unroll
            for (int nt = 0; nt < 4; ++nt)
                acc[mt][nt] = __builtin_amdgcn_mfma_f32_16x16x32_bf16(
                    af[mt], bfr[nt], acc[mt][nt], 0, 0, 0);
        __syncthreads();
    }
}

// ---------------------------------------------------------------------------
// Merged QKV GEMM (stacked N=3072) with fused epilogues.
//  n_global < 1024:  K -> LN(kln) -> Kb
//  1024..2047:       Q -> LN(qln) * 0.125*log2e -> Qb
//  2048..3071:       V -> transposed store -> Vt [bh][d][t]
// 64-wide N-tile == exactly one head; each output row lives in one quad.
// ---------------------------------------------------------------------------
__global__ __launch_bounds__(256) void gemm_qkv(
    const ushort* __restrict__ A,
    const ushort* __restrict__ W0, const ushort* __restrict__ W1,
    const ushort* __restrict__ W2,
    ushort* __restrict__ Kb, ushort* __restrict__ Qb, ushort* __restrict__ Vt,
    const float* __restrict__ kw, const float* __restrict__ kbias,
    const float* __restrict__ qw, const float* __restrict__ qbias)
{
    __shared__ ushort As[128 * 32];   // 8 KB
    __shared__ ushort Bs[64 * 32];    // 4 KB
    const int n0g = blockIdx.x * 64;          // 0..3071
    const int z   = n0g >> 10;                // 0:K 1:Q 2:V
    const int n0  = n0g & 1023;
    const int m0  = blockIdx.y * 128;
    const ushort* W = (z == 0) ? W0 : (z == 1) ? W1 : W2;

    f32x4 acc[2][4];
    gemm_core64(A, W, m0, n0, As, Bs, acc);

    const int lane = threadIdx.x & 63, w = threadIdx.x >> 6;
    const int quad = lane >> 4, l16 = lane & 15;
    const int row0 = m0 + w * 32;

    if (z < 2) {
        ushort* C = z ? Qb : Kb;
        const float* lw = z ? qw : kw;
        const float* lb = z ? qbias : kbias;
        const float scale = z ? (0.125f * LOG2E) : 1.0f;
        float wv[4], bv_[4];
#pragma unroll
        for (int nt = 0; nt < 4; ++nt) {
            wv[nt]  = lw[nt * 16 + l16];
            bv_[nt] = lb[nt * 16 + l16];
        }
#pragma unroll
        for (int mt = 0; mt < 2; ++mt)
#pragma unroll
            for (int r = 0; r < 4; ++r) {
                float v[4], d[4];
#pragma unroll
                for (int nt = 0; nt < 4; ++nt) v[nt] = acc[mt][nt][r];
                float s = v[0] + v[1] + v[2] + v[3];
                s += __shfl_xor(s, 1); s += __shfl_xor(s, 2);
                s += __shfl_xor(s, 4); s += __shfl_xor(s, 8);
                float mu = s * (1.0f / 64.0f);
                float q2 = 0.f;
#pragma unroll
                for (int nt = 0; nt < 4; ++nt) { d[nt] = v[nt] - mu; q2 += d[nt] * d[nt]; }
                q2 += __shfl_xor(q2, 1); q2 += __shfl_xor(q2, 2);
                q2 += __shfl_xor(q2, 4); q2 += __shfl_xor(q2, 8);
                float rin = rsqrtf(q2 * (1.0f / 64.0f) + 1e-5f);
                int row = row0 + mt * 16 + quad * 4 + r;
#pragma unroll
                for (int nt = 0; nt < 4; ++nt)
                    C[(size_t)row * E_DIM + n0 + nt * 16 + l16] =
                        f2bf((d[nt] * rin * wv[nt] + bv_[nt]) * scale);
            }
    } else {
        // V: transposed store Vt[(b*NH+h)*64 + d][t]
        const int bidx = m0 >> 11;
        const int hh   = n0 >> 6;
        const int t0   = (m0 & 2047) + w * 32;
#pragma unroll
        for (int mt = 0; mt < 2; ++mt)
#pragma unroll
            for (int nt = 0; nt < 4; ++nt) {
                ushort4 pk = make_ushort4(f2bf(acc[mt][nt][0]), f2bf(acc[mt][nt][1]),
                                          f2bf(acc[mt][nt][2]), f2bf(acc[mt][nt][3]));
                size_t off = ((size_t)(bidx * NH + hh) * 64 + nt * 16 + l16) * T_SEQ
                             + t0 + mt * 16 + quad * 4;
                *(ushort4*)(Vt + off) = pk;
            }
    }
}

// ---------------------------------------------------------------------------
// Output GEMM, 128x64 tiles (grid 16x32 = 512 blocks), fp32 store.
// ---------------------------------------------------------------------------
__global__ __launch_bounds__(256) void gemm_o(
    const ushort* __restrict__ A, const ushort* __restrict__ W,
    float* __restrict__ C)
{
    __shared__ ushort As[128 * 32];
    __shared__ ushort Bs[64 * 32];
    const int m0 = blockIdx.y * 128, n0 = blockIdx.x * 64;
    f32x4 acc[2][4];
    gemm_core64(A, W, m0, n0, As, Bs, acc);

    const int lane = threadIdx.x & 63, w = threadIdx.x >> 6;
    const int quad = lane >> 4, l16 = lane & 15;
    const int row0 = m0 + w * 32;
#pragma unroll
    for (int mt = 0; mt < 2; ++mt)
#pragma unroll
        for (int nt = 0; nt < 4; ++nt)
#pragma unroll
            for (int r = 0; r < 4; ++r)
                C[(size_t)(row0 + mt * 16 + quad * 4 + r) * E_DIM
                  + n0 + nt * 16 + l16] = acc[mt][nt][r];
}

// ---------------------------------------------------------------------------
// Flash attention v4 (causal, bf16 MFMA, exp2 fixed-max softmax).
// Block = (b,h) x 128 q-rows, 4 waves; wave owns 32 q-rows (2 A-frags).
// K/V LDS staging amortized over 2x rows -> LDS cyc/MFMA 19.3 -> 13.3.
// Grid 512, balance pairs {q0, 15-q0} -> 34 iters per CU-class.
// Fully-masked waves skip compute (still hit barriers).
// ---------------------------------------------------------------------------
__global__ __launch_bounds__(256) void flash_attn4(
    const ushort* __restrict__ Qg, const ushort* __restrict__ Kg,
    const ushort* __restrict__ Vt, ushort* __restrict__ O)
{
    __shared__ ushort Ks[2][64 * 64];   // 16 KB
    __shared__ ushort Vs[2][64 * 64];   // 16 KB
    __shared__ ushort Ps[4][32 * 64];   // 16 KB (per-wave 32x64 P)

    const int tid  = threadIdx.x;
    const int lane = tid & 63, w = tid >> 6;
    const int quad = lane >> 4, l16 = lane & 15;

    // balance swizzle: 512 blocks, slot s of class c gets qt in {q0, 15-q0}
    const int L = blockIdx.x;
    const int c = L & 255, s = L >> 8;
    const int q0 = c >> 5;              // 0..7
    const int bh = c & 31;
    const int qt = s ? (15 - q0) : q0;  // 128-row q-tile index
    const int b = bh >> 4, h = bh & 15;

    const ushort* Qbase = Qg + ((size_t)b * T_SEQ) * E_DIM + h * HS;
    const ushort* Kbase = Kg + ((size_t)b * T_SEQ) * E_DIM + h * HS;
    const ushort* Vbase = Vt + ((size_t)bh * HS) * T_SEQ;   // [d][t]

    const int rloc = lane >> 3;
    const int gswc = (lane & 7) ^ rloc;     // swizzled global chunk
    const int sw   = l16 & 7;               // frag-read xor factor

    const int base_w = qt * 128 + w * 32;   // wave's first q-row

    // Q fragments in registers (pre-scaled by 0.125*log2e in LN)
    bf16x8 aq[2][2];
#pragma unroll
    for (int u = 0; u < 2; ++u)
#pragma unroll
        for (int ks = 0; ks < 2; ++ks)
            aq[u][ks] = *(const bf16x8*)(Qbase
                + (size_t)(base_w + u * 16 + l16) * E_DIM + ks * 32 + quad * 8);

    const f32x4 zero = {0.f, 0.f, 0.f, 0.f};
    f32x4 o_acc[2][4];
#pragma unroll
    for (int u = 0; u < 2; ++u)
#pragma unroll
        for (int dt = 0; dt < 4; ++dt) o_acc[u][dt] = zero;
    float l_acc[2][4] = {{0.f,0.f,0.f,0.f},{0.f,0.f,0.f,0.f}};

    // initial stage into buffer 0
#pragma unroll
    for (int i = 0; i < 2; ++i) {
        int cc = w * 2 + i, row = cc * 8 + rloc;
        load_lds16(Kbase + (size_t)row * E_DIM + gswc * 8, Ks[0] + cc * 512);
        load_lds16(Vbase + (size_t)row * T_SEQ + gswc * 8, Vs[0] + cc * 512);
    }

    const float M8 = 8.0f * LOG2E;
    const int ntiles = 2 * qt + 2;

    for (int jt = 0; jt < ntiles; ++jt) {
        const int buf = jt & 1;
        __syncthreads();   // drains vmcnt -> buf ready; syncs buffer reuse
        if (jt + 1 < ntiles) {
#pragma unroll
            for (int i = 0; i < 2; ++i) {
                int cc = w * 2 + i, row = cc * 8 + rloc;
                load_lds16(Kbase + (size_t)(jt + 1) * 64 * E_DIM
                           + (size_t)row * E_DIM + gswc * 8, Ks[buf ^ 1] + cc * 512);
                load_lds16(Vbase + (size_t)row * T_SEQ + (jt + 1) * 64 + gswc * 8,
                           Vs[buf ^ 1] + cc * 512);
            }
        }

        if (jt * 64 > base_w + 31) continue;   // fully masked for this wave

        // S = Q K^T (32 q-rows x 64 k-cols), exp2 domain
        f32x4 sa[2][4];
#pragma unroll
        for (int u = 0; u < 2; ++u)
#pragma unroll
            for (int nt = 0; nt < 4; ++nt) sa[u][nt] = zero;
#pragma unroll
        for (int ks = 0; ks < 2; ++ks) {
            int cp = ((ks * 4 + quad) ^ sw) * 8;
            bf16x8 bk[4];
#pragma unroll
            for (int nt = 0; nt < 4; ++nt)
                bk[nt] = *(const bf16x8*)(Ks[buf] + (nt * 16 + l16) * 64 + cp);
#pragma unroll
            for (int u = 0; u < 2; ++u)
#pragma unroll
                for (int nt = 0; nt < 4; ++nt)
                    sa[u][nt] = __builtin_amdgcn_mfma_f32_16x16x32_bf16(
                        aq[u][ks], bk[nt], sa[u][nt], 0, 0, 0);
        }

        if (jt * 64 + 63 > base_w) {   // diagonal overlap: causal mask
#pragma unroll
            for (int u = 0; u < 2; ++u)
#pragma unroll
                for (int nt = 0; nt < 4; ++nt)
#pragma unroll
                    for (int r = 0; r < 4; ++r)
                        if (jt * 64 + nt * 16 + l16 >
                            base_w + u * 16 + quad * 4 + r) sa[u][nt][r] = -1e30f;
        }

        // p = exp2(s - 8*log2e); per-lane l accumulation
#pragma unroll
        for (int u = 0; u < 2; ++u)
#pragma unroll
            for (int nt = 0; nt < 4; ++nt)
#pragma unroll
                for (int r = 0; r < 4; ++r) {
                    float p = __builtin_amdgcn_exp2f(sa[u][nt][r] - M8);
                    sa[u][nt][r] = p;
                    l_acc[u][r] += p;
                }

        // P -> per-wave LDS (swizzled chunks), truncating bf16 pack
#pragma unroll
        for (int u = 0; u < 2; ++u)
#pragma unroll
            for (int nt = 0; nt < 4; ++nt)
#pragma unroll
                for (int r = 0; r < 4; ++r) {
                    int row = u * 16 + quad * 4 + r;
                    int cp2 = (nt * 2 + (l16 >> 3)) ^ (row & 7);
                    Ps[w][row * 64 + cp2 * 8 + (l16 & 7)] = f2bf_trunc(sa[u][nt][r]);
                }

        // O += P @ V
#pragma unroll
        for (int ks = 0; ks < 2; ++ks) {
            int cp = ((ks * 4 + quad) ^ sw) * 8;
            bf16x8 bv[4];
#pragma unroll
            for (int dt = 0; dt < 4; ++dt)
                bv[dt] = *(const bf16x8*)(Vs[buf] + (dt * 16 + l16) * 64 + cp);
#pragma unroll
            for (int u = 0; u < 2; ++u) {
                bf16x8 ap = *(const bf16x8*)(Ps[w] + (u * 16 + l16) * 64 + cp);
#pragma unroll
                for (int dt = 0; dt < 4; ++dt)
                    o_acc[u][dt] = __builtin_amdgcn_mfma_f32_16x16x32_bf16(
                        ap, bv[dt], o_acc[u][dt], 0, 0, 0);
            }
        }
    }

    // Epilogue: l reduce within quad, divide, store bf16 [b,t][h*64+d]
#pragma unroll
    for (int u = 0; u < 2; ++u)
#pragma unroll
        for (int r = 0; r < 4; ++r) {
            float Lr = l_acc[u][r];
            Lr += __shfl_xor(Lr, 1); Lr += __shfl_xor(Lr, 2);
            Lr += __shfl_xor(Lr, 4); Lr += __shfl_xor(Lr, 8);
            float inv = 1.0f / Lr;
            int trow = base_w + u * 16 + quad * 4 + r;
#pragma unroll
            for (int dt = 0; dt < 4; ++dt)
                O[((size_t)b * T_SEQ + trow) * E_DIM + h * HS + dt * 16 + l16] =
                    f2bf(o_acc[u][dt][r] * inv);
        }
}

// ---------------------------------------------------------------------------
extern "C" void kernel_launch(void* const* d_in, const int* in_sizes, int n_in,
                              void* d_out, int out_size, void* d_ws, size_t ws_size,
                              hipStream_t stream) {
    const float* x     = (const float*)d_in[0];
    const float* Wk    = (const float*)d_in[1];
    const float* Wq    = (const float*)d_in[2];
    const float* Wv    = (const float*)d_in[3];
    const float* Wu    = (const float*)d_in[4];
    const float* kln_w = (const float*)d_in[5];
    const float* kln_b = (const float*)d_in[6];
    const float* qln_w = (const float*)d_in[7];
    const float* qln_b = (const float*)d_in[8];
    float* out = (float*)d_out;

    const size_t NE = (size_t)M_ROWS * E_DIM;   // 4M elems
    const size_t NW = (size_t)E_DIM * E_DIM;    // 1M elems
    ushort* xb  = (ushort*)d_ws;                // 4M
    ushort* Wkb = xb  + NE;                     // 1M each
    ushort* Wqb = Wkb + NW;
    ushort* Wvb = Wqb + NW;
    ushort* Wub = Wvb + NW;
    ushort* Kb  = Wub + NW;                     // 4M
    ushort* Qb  = Kb  + NE;                     // 4M
    ushort* Vt  = Qb  + NE;                     // 4M, [bh][d][t]
    ushort* Ob  = Vt  + NE;                     // 4M

    // 1) fp32 -> bf16
    cvt_all<<<8192, 256, 0, stream>>>(x, Wk, Wq, Wv, Wu, xb, Wkb, Wqb, Wvb, Wub);

    // 2) Merged K/Q/V projections (stacked N=3072) with fused LN + V-transpose
    gemm_qkv<<<dim3(3 * E_DIM / 64, M_ROWS / 128), 256, 0, stream>>>(
        xb, Wkb, Wqb, Wvb, Kb, Qb, Vt, kln_w, kln_b, qln_w, qln_b);

    // 3) Causal flash attention (128-row blocks, balanced grid)
    flash_attn4<<<512, 256, 0, stream>>>(Qb, Kb, Vt, Ob);

    // 4) Output projection -> fp32 out
    gemm_o<<<dim3(E_DIM / 64, M_ROWS / 128), 256, 0, stream>>>(Ob, Wub, out);
}

// Round 7
// 190.825 us; speedup vs baseline: 1.0736x; 1.0736x over previous
//
#include <hip/hip_runtime.h>
#include <math.h>

// Problem constants (B=2, T=2048, E=1024, H=16, S=64)
#define T_SEQ 2048
#define E_DIM 1024
#define NH    16
#define HS    64
#define NB    2
#define M_ROWS 4096

typedef __attribute__((ext_vector_type(8))) short bf16x8;
typedef __attribute__((ext_vector_type(4))) float f32x4;

#define AS1 __attribute__((address_space(1)))
#define AS3 __attribute__((address_space(3)))

#define LOG2E 1.4426950408889634f

__device__ __forceinline__ ushort f2bf(float f) {
    union { float f; unsigned u; } c; c.f = f;
    unsigned r = c.u + 0x7fffu + ((c.u >> 16) & 1u);
    return (ushort)(r >> 16);
}
__device__ __forceinline__ ushort f2bf_trunc(float f) {
    union { float f; unsigned u; } c; c.f = f;
    return (ushort)(c.u >> 16);
}

__device__ __forceinline__ void load_lds16(const ushort* g, ushort* l) {
    // 16B per lane, LDS dest = wave-uniform base + lane*16 (HW behavior)
    __builtin_amdgcn_global_load_lds((const AS1 unsigned int*)g,
                                     (AS3 unsigned int*)l, 16, 0, 0);
}

// ---------------------------------------------------------------------------
// fp32 -> bf16 conversion for x and the four weight matrices.
// ---------------------------------------------------------------------------
__global__ __launch_bounds__(256) void cvt_all(
    const float* __restrict__ x,  const float* __restrict__ Wk,
    const float* __restrict__ Wq, const float* __restrict__ Wv,
    const float* __restrict__ Wu,
    ushort* __restrict__ xb,  ushort* __restrict__ Wkb,
    ushort* __restrict__ Wqb, ushort* __restrict__ Wvb,
    ushort* __restrict__ Wub)
{
    int i4 = blockIdx.x * 256 + threadIdx.x;   // 0 .. 2M-1 (float4 units)
    int region = i4 >> 18;
    const float* src; ushort* dst; int off;
    if      (region < 4)  { src = x;  dst = xb;  off = i4; }
    else if (region == 4) { src = Wk; dst = Wkb; off = i4 - (4 << 18); }
    else if (region == 5) { src = Wq; dst = Wqb; off = i4 - (5 << 18); }
    else if (region == 6) { src = Wv; dst = Wvb; off = i4 - (6 << 18); }
    else                  { src = Wu; dst = Wub; off = i4 - (7 << 18); }
    float4 v = *(const float4*)(src + (size_t)off * 4);
    ushort4 o; o.x = f2bf(v.x); o.y = f2bf(v.y); o.z = f2bf(v.z); o.w = f2bf(v.w);
    *(ushort4*)(dst + (size_t)off * 4) = o;
}

// ---------------------------------------------------------------------------
// bf16 MFMA GEMM core (m97 structure): C[M,N] = A[M,K] * W[N,K]^T, K=1024.
// 128x128 tile, BK=32, 4 waves in 2x2, wave = 64x64 via 4x4 16x16x32 MFMAs.
// 16 MFMAs per wave per barrier-pair — the proven sweet spot (m105/m112).
// ---------------------------------------------------------------------------
__device__ __forceinline__ void gemm_core(
    const ushort* __restrict__ A, const ushort* __restrict__ W,
    int m0, int n0, ushort* As, ushort* Bs, f32x4 acc[4][4])
{
    const int tid  = threadIdx.x;
    const int lane = tid & 63, w = tid >> 6;
    const int quad = lane >> 4, l16 = lane & 15;
    const int wm = w & 1, wn = w >> 1;

    const int rl   = lane >> 2;                       // row-in-chunk 0..15
    const int gsw  = (lane & 3) ^ ((lane >> 3) & 3);  // swizzled global chunk
    const int fsw  = (l16 >> 1) & 3;                  // frag-read xor factor

    const f32x4 zero = {0.f, 0.f, 0.f, 0.f};
#pragma unroll
    for (int mt = 0; mt < 4; ++mt)
#pragma unroll
        for (int nt = 0; nt < 4; ++nt) acc[mt][nt] = zero;

    for (int k0 = 0; k0 < E_DIM; k0 += 32) {
#pragma unroll
        for (int i = 0; i < 2; ++i) {
            int c = i * 4 + w;                 // chunk 0..7 (16 rows x 64B)
            int row = c * 16 + rl;
            load_lds16(A + (size_t)(m0 + row) * E_DIM + k0 + gsw * 8, As + c * 512);
            load_lds16(W + (size_t)(n0 + row) * E_DIM + k0 + gsw * 8, Bs + c * 512);
        }
        __syncthreads();
        bf16x8 af[4], bfr[4];
#pragma unroll
        for (int mt = 0; mt < 4; ++mt)
            af[mt] = *(const bf16x8*)(As + (wm * 64 + mt * 16 + l16) * 32
                                      + ((quad ^ fsw) * 8));
#pragma unroll
        for (int nt = 0; nt < 4; ++nt)
            bfr[nt] = *(const bf16x8*)(Bs + (wn * 64 + nt * 16 + l16) * 32
                                       + ((quad ^ fsw) * 8));
#pragma unroll
        for (int mt = 0; mt < 4; ++mt)
#pragma unroll
            for (int nt = 0; nt < 4; ++nt)
                acc[mt][nt] = __builtin_amdgcn_mfma_f32_16x16x32_bf16(
                    af[mt], bfr[nt], acc[mt][nt], 0, 0, 0);
        __syncthreads();
    }
}

// ---------------------------------------------------------------------------
// QKV GEMM (z-grid) with fused epilogues:
//  z=0: K -> LN(kln) -> Kb
//  z=1: Q -> LN(qln) * 0.125*log2e -> Qb
//  z=2: V -> transposed store -> Vt [bh][d][t]
// Wave's 64 cols == one head (col0 % 64 == 0), each row lives in one quad.
// ---------------------------------------------------------------------------
__global__ __launch_bounds__(256) void gemm_qkv(
    const ushort* __restrict__ A,
    const ushort* __restrict__ W0, const ushort* __restrict__ W1,
    const ushort* __restrict__ W2,
    ushort* __restrict__ Kb, ushort* __restrict__ Qb, ushort* __restrict__ Vt,
    const float* __restrict__ kw, const float* __restrict__ kbias,
    const float* __restrict__ qw, const float* __restrict__ qbias)
{
    __shared__ ushort As[128 * 32];
    __shared__ ushort Bs[128 * 32];
    const int z = blockIdx.z;
    const ushort* W = (z == 0) ? W0 : (z == 1) ? W1 : W2;
    const int m0 = blockIdx.y * 128, n0 = blockIdx.x * 128;
    f32x4 acc[4][4];
    gemm_core(A, W, m0, n0, As, Bs, acc);

    const int lane = threadIdx.x & 63, w = threadIdx.x >> 6;
    const int quad = lane >> 4, l16 = lane & 15;
    const int wm = w & 1, wn = w >> 1;
    const int row0 = m0 + wm * 64;
    const int col0 = n0 + wn * 64;

    if (z < 2) {
        ushort* C = z ? Qb : Kb;
        const float* lw = z ? qw : kw;
        const float* lb = z ? qbias : kbias;
        const float scale = z ? (0.125f * LOG2E) : 1.0f;
        float wv[4], bv_[4];
#pragma unroll
        for (int nt = 0; nt < 4; ++nt) {
            wv[nt]  = lw[nt * 16 + l16];
            bv_[nt] = lb[nt * 16 + l16];
        }
#pragma unroll
        for (int mt = 0; mt < 4; ++mt)
#pragma unroll
            for (int r = 0; r < 4; ++r) {
                float v[4], d[4];
#pragma unroll
                for (int nt = 0; nt < 4; ++nt) v[nt] = acc[mt][nt][r];
                float s = v[0] + v[1] + v[2] + v[3];
                s += __shfl_xor(s, 1); s += __shfl_xor(s, 2);
                s += __shfl_xor(s, 4); s += __shfl_xor(s, 8);
                float mu = s * (1.0f / 64.0f);
                float q2 = 0.f;
#pragma unroll
                for (int nt = 0; nt < 4; ++nt) { d[nt] = v[nt] - mu; q2 += d[nt] * d[nt]; }
                q2 += __shfl_xor(q2, 1); q2 += __shfl_xor(q2, 2);
                q2 += __shfl_xor(q2, 4); q2 += __shfl_xor(q2, 8);
                float rin = rsqrtf(q2 * (1.0f / 64.0f) + 1e-5f);
                int row = row0 + mt * 16 + quad * 4 + r;
#pragma unroll
                for (int nt = 0; nt < 4; ++nt)
                    C[(size_t)row * E_DIM + col0 + nt * 16 + l16] =
                        f2bf((d[nt] * rin * wv[nt] + bv_[nt]) * scale);
            }
    } else {
        // V: transposed store Vt[(b*NH+h)*64 + d][t]
        const int bidx = m0 >> 11;
        const int hh   = col0 >> 6;
        const int t0   = (m0 & 2047) + wm * 64;
#pragma unroll
        for (int mt = 0; mt < 4; ++mt)
#pragma unroll
            for (int nt = 0; nt < 4; ++nt) {
                ushort4 pk = make_ushort4(f2bf(acc[mt][nt][0]), f2bf(acc[mt][nt][1]),
                                          f2bf(acc[mt][nt][2]), f2bf(acc[mt][nt][3]));
                size_t off = ((size_t)(bidx * NH + hh) * 64 + nt * 16 + l16) * T_SEQ
                             + t0 + mt * 16 + quad * 4;
                *(ushort4*)(Vt + off) = pk;
            }
    }
}

// ---------------------------------------------------------------------------
// Output GEMM, 128(M)x64(N) tiles -> 512 blocks (2/CU), 2x2 wave grid,
// wave = 64x32 via 4x2 MFMAs (A-frags reused across the wave row).
// ---------------------------------------------------------------------------
__global__ __launch_bounds__(256) void gemm_o(
    const ushort* __restrict__ A, const ushort* __restrict__ W,
    float* __restrict__ C)
{
    __shared__ ushort As[128 * 32];   // 8 KB
    __shared__ ushort Bs[64 * 32];    // 4 KB
    const int tid  = threadIdx.x;
    const int lane = tid & 63, w = tid >> 6;
    const int quad = lane >> 4, l16 = lane & 15;
    const int wm = w & 1, wn = w >> 1;
    const int m0 = blockIdx.y * 128, n0 = blockIdx.x * 64;

    const int rl  = lane >> 2;
    const int gsw = (lane & 3) ^ ((lane >> 3) & 3);
    const int fsw = (l16 >> 1) & 3;

    const f32x4 zero = {0.f, 0.f, 0.f, 0.f};
    f32x4 acc[4][2];
#pragma unroll
    for (int mt = 0; mt < 4; ++mt)
#pragma unroll
        for (int nt = 0; nt < 2; ++nt) acc[mt][nt] = zero;

    for (int k0 = 0; k0 < E_DIM; k0 += 32) {
#pragma unroll
        for (int i = 0; i < 2; ++i) {
            int c = i * 4 + w;
            int row = c * 16 + rl;
            load_lds16(A + (size_t)(m0 + row) * E_DIM + k0 + gsw * 8, As + c * 512);
        }
        {
            int row = w * 16 + rl;
            load_lds16(W + (size_t)(n0 + row) * E_DIM + k0 + gsw * 8, Bs + w * 512);
        }
        __syncthreads();
        bf16x8 af[4], bfr[2];
#pragma unroll
        for (int mt = 0; mt < 4; ++mt)
            af[mt] = *(const bf16x8*)(As + (wm * 64 + mt * 16 + l16) * 32
                                      + ((quad ^ fsw) * 8));
#pragma unroll
        for (int nt = 0; nt < 2; ++nt)
            bfr[nt] = *(const bf16x8*)(Bs + (wn * 32 + nt * 16 + l16) * 32
                                       + ((quad ^ fsw) * 8));
#pragma unroll
        for (int mt = 0; mt < 4; ++mt)
#pragma unroll
            for (int nt = 0; nt < 2; ++nt)
                acc[mt][nt] = __builtin_amdgcn_mfma_f32_16x16x32_bf16(
                    af[mt], bfr[nt], acc[mt][nt], 0, 0, 0);
        __syncthreads();
    }

    const int row0 = m0 + wm * 64;
    const int col0 = n0 + wn * 32;
#pragma unroll
    for (int mt = 0; mt < 4; ++mt)
#pragma unroll
        for (int nt = 0; nt < 2; ++nt)
#pragma unroll
            for (int r = 0; r < 4; ++r)
                C[(size_t)(row0 + mt * 16 + quad * 4 + r) * E_DIM
                  + col0 + nt * 16 + l16] = acc[mt][nt][r];
}

// ---------------------------------------------------------------------------
// Flash attention v4 (causal, bf16 MFMA, exp2 fixed-max softmax).
// Block = (b,h) x 128 q-rows, 4 waves; wave owns 32 q-rows (2 A-frags).
// Grid 512, balance pairs {q0, 15-q0} -> 34 iters per CU-class.
// ---------------------------------------------------------------------------
__global__ __launch_bounds__(256) void flash_attn4(
    const ushort* __restrict__ Qg, const ushort* __restrict__ Kg,
    const ushort* __restrict__ Vt, ushort* __restrict__ O)
{
    __shared__ ushort Ks[2][64 * 64];   // 16 KB
    __shared__ ushort Vs[2][64 * 64];   // 16 KB
    __shared__ ushort Ps[4][32 * 64];   // 16 KB (per-wave 32x64 P)

    const int tid  = threadIdx.x;
    const int lane = tid & 63, w = tid >> 6;
    const int quad = lane >> 4, l16 = lane & 15;

    const int L = blockIdx.x;
    const int c = L & 255, s = L >> 8;
    const int q0 = c >> 5;              // 0..7
    const int bh = c & 31;
    const int qt = s ? (15 - q0) : q0;  // 128-row q-tile index
    const int b = bh >> 4, h = bh & 15;

    const ushort* Qbase = Qg + ((size_t)b * T_SEQ) * E_DIM + h * HS;
    const ushort* Kbase = Kg + ((size_t)b * T_SEQ) * E_DIM + h * HS;
    const ushort* Vbase = Vt + ((size_t)bh * HS) * T_SEQ;   // [d][t]

    const int rloc = lane >> 3;
    const int gswc = (lane & 7) ^ rloc;     // swizzled global chunk
    const int sw   = l16 & 7;               // frag-read xor factor

    const int base_w = qt * 128 + w * 32;   // wave's first q-row

    // Q fragments in registers (pre-scaled by 0.125*log2e in LN)
    bf16x8 aq[2][2];
#pragma unroll
    for (int u = 0; u < 2; ++u)
#pragma unroll
        for (int ks = 0; ks < 2; ++ks)
            aq[u][ks] = *(const bf16x8*)(Qbase
                + (size_t)(base_w + u * 16 + l16) * E_DIM + ks * 32 + quad * 8);

    const f32x4 zero = {0.f, 0.f, 0.f, 0.f};
    f32x4 o_acc[2][4];
#pragma unroll
    for (int u = 0; u < 2; ++u)
#pragma unroll
        for (int dt = 0; dt < 4; ++dt) o_acc[u][dt] = zero;
    float l_acc[2][4] = {{0.f,0.f,0.f,0.f},{0.f,0.f,0.f,0.f}};

    // initial stage into buffer 0
#pragma unroll
    for (int i = 0; i < 2; ++i) {
        int cc = w * 2 + i, row = cc * 8 + rloc;
        load_lds16(Kbase + (size_t)row * E_DIM + gswc * 8, Ks[0] + cc * 512);
        load_lds16(Vbase + (size_t)row * T_SEQ + gswc * 8, Vs[0] + cc * 512);
    }

    const float M8 = 8.0f * LOG2E;
    const int ntiles = 2 * qt + 2;

    for (int jt = 0; jt < ntiles; ++jt) {
        const int buf = jt & 1;
        __syncthreads();   // drains vmcnt -> buf ready; syncs buffer reuse
        if (jt + 1 < ntiles) {
#pragma unroll
            for (int i = 0; i < 2; ++i) {
                int cc = w * 2 + i, row = cc * 8 + rloc;
                load_lds16(Kbase + (size_t)(jt + 1) * 64 * E_DIM
                           + (size_t)row * E_DIM + gswc * 8, Ks[buf ^ 1] + cc * 512);
                load_lds16(Vbase + (size_t)row * T_SEQ + (jt + 1) * 64 + gswc * 8,
                           Vs[buf ^ 1] + cc * 512);
            }
        }

        if (jt * 64 > base_w + 31) continue;   // fully masked for this wave

        // S = Q K^T (32 q-rows x 64 k-cols), exp2 domain
        f32x4 sa[2][4];
#pragma unroll
        for (int u = 0; u < 2; ++u)
#pragma unroll
            for (int nt = 0; nt < 4; ++nt) sa[u][nt] = zero;
#pragma unroll
        for (int ks = 0; ks < 2; ++ks) {
            int cp = ((ks * 4 + quad) ^ sw) * 8;
            bf16x8 bk[4];
#pragma unroll
            for (int nt = 0; nt < 4; ++nt)
                bk[nt] = *(const bf16x8*)(Ks[buf] + (nt * 16 + l16) * 64 + cp);
#pragma unroll
            for (int u = 0; u < 2; ++u)
#pragma unroll
                for (int nt = 0; nt < 4; ++nt)
                    sa[u][nt] = __builtin_amdgcn_mfma_f32_16x16x32_bf16(
                        aq[u][ks], bk[nt], sa[u][nt], 0, 0, 0);
        }

        if (jt * 64 + 63 > base_w) {   // diagonal overlap: causal mask
#pragma unroll
            for (int u = 0; u < 2; ++u)
#pragma unroll
                for (int nt = 0; nt < 4; ++nt)
#pragma unroll
                    for (int r = 0; r < 4; ++r)
                        if (jt * 64 + nt * 16 + l16 >
                            base_w + u * 16 + quad * 4 + r) sa[u][nt][r] = -1e30f;
        }

        // p = exp2(s - 8*log2e); per-lane l accumulation
#pragma unroll
        for (int u = 0; u < 2; ++u)
#pragma unroll
            for (int nt = 0; nt < 4; ++nt)
#pragma unroll
                for (int r = 0; r < 4; ++r) {
                    float p = __builtin_amdgcn_exp2f(sa[u][nt][r] - M8);
                    sa[u][nt][r] = p;
                    l_acc[u][r] += p;
                }

        // P -> per-wave LDS (swizzled chunks), truncating bf16 pack
#pragma unroll
        for (int u = 0; u < 2; ++u)
#pragma unroll
            for (int nt = 0; nt < 4; ++nt)
#pragma unroll
                for (int r = 0; r < 4; ++r) {
                    int row = u * 16 + quad * 4 + r;
                    int cp2 = (nt * 2 + (l16 >> 3)) ^ (row & 7);
                    Ps[w][row * 64 + cp2 * 8 + (l16 & 7)] = f2bf_trunc(sa[u][nt][r]);
                }

        // O += P @ V
#pragma unroll
        for (int ks = 0; ks < 2; ++ks) {
            int cp = ((ks * 4 + quad) ^ sw) * 8;
            bf16x8 bv[4];
#pragma unroll
            for (int dt = 0; dt < 4; ++dt)
                bv[dt] = *(const bf16x8*)(Vs[buf] + (dt * 16 + l16) * 64 + cp);
#pragma unroll
            for (int u = 0; u < 2; ++u) {
                bf16x8 ap = *(const bf16x8*)(Ps[w] + (u * 16 + l16) * 64 + cp);
#pragma unroll
                for (int dt = 0; dt < 4; ++dt)
                    o_acc[u][dt] = __builtin_amdgcn_mfma_f32_16x16x32_bf16(
                        ap, bv[dt], o_acc[u][dt], 0, 0, 0);
            }
        }
    }

    // Epilogue: l reduce within quad, divide, store bf16 [b,t][h*64+d]
#pragma unroll
    for (int u = 0; u < 2; ++u)
#pragma unroll
        for (int r = 0; r < 4; ++r) {
            float Lr = l_acc[u][r];
            Lr += __shfl_xor(Lr, 1); Lr += __shfl_xor(Lr, 2);
            Lr += __shfl_xor(Lr, 4); Lr += __shfl_xor(Lr, 8);
            float inv = 1.0f / Lr;
            int trow = base_w + u * 16 + quad * 4 + r;
#pragma unroll
            for (int dt = 0; dt < 4; ++dt)
                O[((size_t)b * T_SEQ + trow) * E_DIM + h * HS + dt * 16 + l16] =
                    f2bf(o_acc[u][dt][r] * inv);
        }
}

// ---------------------------------------------------------------------------
extern "C" void kernel_launch(void* const* d_in, const int* in_sizes, int n_in,
                              void* d_out, int out_size, void* d_ws, size_t ws_size,
                              hipStream_t stream) {
    const float* x     = (const float*)d_in[0];
    const float* Wk    = (const float*)d_in[1];
    const float* Wq    = (const float*)d_in[2];
    const float* Wv    = (const float*)d_in[3];
    const float* Wu    = (const float*)d_in[4];
    const float* kln_w = (const float*)d_in[5];
    const float* kln_b = (const float*)d_in[6];
    const float* qln_w = (const float*)d_in[7];
    const float* qln_b = (const float*)d_in[8];
    float* out = (float*)d_out;

    const size_t NE = (size_t)M_ROWS * E_DIM;   // 4M elems
    const size_t NW = (size_t)E_DIM * E_DIM;    // 1M elems
    ushort* xb  = (ushort*)d_ws;                // 4M
    ushort* Wkb = xb  + NE;                     // 1M each
    ushort* Wqb = Wkb + NW;
    ushort* Wvb = Wqb + NW;
    ushort* Wub = Wvb + NW;
    ushort* Kb  = Wub + NW;                     // 4M
    ushort* Qb  = Kb  + NE;                     // 4M
    ushort* Vt  = Qb  + NE;                     // 4M, [bh][d][t]
    ushort* Ob  = Vt  + NE;                     // 4M

    // 1) fp32 -> bf16
    cvt_all<<<8192, 256, 0, stream>>>(x, Wk, Wq, Wv, Wu, xb, Wkb, Wqb, Wvb, Wub);

    // 2) K/Q/V projections (128x128 z-grid) with fused LN + V-transpose
    gemm_qkv<<<dim3(E_DIM / 128, M_ROWS / 128, 3), 256, 0, stream>>>(
        xb, Wkb, Wqb, Wvb, Kb, Qb, Vt, kln_w, kln_b, qln_w, qln_b);

    // 3) Causal flash attention (128-row blocks, balanced grid)
    flash_attn4<<<512, 256, 0, stream>>>(Qb, Kb, Vt, Ob);

    // 4) Output projection -> fp32 out
    gemm_o<<<dim3(E_DIM / 64, M_ROWS / 128), 256, 0, stream>>>(Ob, Wub, out);
}

// Round 9
// 181.851 us; speedup vs baseline: 1.1266x; 1.0493x over previous
//
#include <hip/hip_runtime.h>
#include <math.h>

// Problem constants (B=2, T=2048, E=1024, H=16, S=64)
#define T_SEQ 2048
#define E_DIM 1024
#define NH    16
#define HS    64
#define NB    2
#define M_ROWS 4096

typedef __attribute__((ext_vector_type(8))) short bf16x8;
typedef __attribute__((ext_vector_type(4))) short bf16x4;
typedef __attribute__((ext_vector_type(4))) float f32x4;

#define AS1 __attribute__((address_space(1)))
#define AS3 __attribute__((address_space(3)))

#define LOG2E 1.4426950408889634f

// 16x16x16 bf16 MFMA (K=16): B-operand k-index (quad*4+j) matches the
// C-layout row index (quad*4+r) — QK^T's S^T accumulator feeds PV directly.
__device__ __forceinline__ f32x4 mfma16(bf16x4 a, bf16x4 b, f32x4 c) {
    return __builtin_amdgcn_mfma_f32_16x16x16bf16_1k(a, b, c, 0, 0, 0);
}

__device__ __forceinline__ ushort f2bf(float f) {
    union { float f; unsigned u; } c; c.f = f;
    unsigned r = c.u + 0x7fffu + ((c.u >> 16) & 1u);
    return (ushort)(r >> 16);
}
__device__ __forceinline__ ushort f2bf_trunc(float f) {
    union { float f; unsigned u; } c; c.f = f;
    return (ushort)(c.u >> 16);
}

__device__ __forceinline__ void load_lds16(const ushort* g, ushort* l) {
    // 16B per lane, LDS dest = wave-uniform base + lane*16 (HW behavior)
    __builtin_amdgcn_global_load_lds((const AS1 unsigned int*)g,
                                     (AS3 unsigned int*)l, 16, 0, 0);
}

// ---------------------------------------------------------------------------
// fp32 -> bf16 conversion for x and the four weight matrices.
// ---------------------------------------------------------------------------
__global__ __launch_bounds__(256) void cvt_all(
    const float* __restrict__ x,  const float* __restrict__ Wk,
    const float* __restrict__ Wq, const float* __restrict__ Wv,
    const float* __restrict__ Wu,
    ushort* __restrict__ xb,  ushort* __restrict__ Wkb,
    ushort* __restrict__ Wqb, ushort* __restrict__ Wvb,
    ushort* __restrict__ Wub)
{
    int i4 = blockIdx.x * 256 + threadIdx.x;   // 0 .. 2M-1 (float4 units)
    int region = i4 >> 18;
    const float* src; ushort* dst; int off;
    if      (region < 4)  { src = x;  dst = xb;  off = i4; }
    else if (region == 4) { src = Wk; dst = Wkb; off = i4 - (4 << 18); }
    else if (region == 5) { src = Wq; dst = Wqb; off = i4 - (5 << 18); }
    else if (region == 6) { src = Wv; dst = Wvb; off = i4 - (6 << 18); }
    else                  { src = Wu; dst = Wub; off = i4 - (7 << 18); }
    float4 v = *(const float4*)(src + (size_t)off * 4);
    ushort4 o; o.x = f2bf(v.x); o.y = f2bf(v.y); o.z = f2bf(v.z); o.w = f2bf(v.w);
    *(ushort4*)(dst + (size_t)off * 4) = o;
}

// ---------------------------------------------------------------------------
// bf16 MFMA GEMM core (m97 structure): C[M,N] = A[M,K] * W[N,K]^T, K=1024.
// 128x128 tile, BK=32, 4 waves in 2x2, wave = 64x64 via 4x4 16x16x32 MFMAs.
// ---------------------------------------------------------------------------
__device__ __forceinline__ void gemm_core(
    const ushort* __restrict__ A, const ushort* __restrict__ W,
    int m0, int n0, ushort* As, ushort* Bs, f32x4 acc[4][4])
{
    const int tid  = threadIdx.x;
    const int lane = tid & 63, w = tid >> 6;
    const int quad = lane >> 4, l16 = lane & 15;
    const int wm = w & 1, wn = w >> 1;

    const int rl   = lane >> 2;                       // row-in-chunk 0..15
    const int gsw  = (lane & 3) ^ ((lane >> 3) & 3);  // swizzled global chunk
    const int fsw  = (l16 >> 1) & 3;                  // frag-read xor factor

    const f32x4 zero = {0.f, 0.f, 0.f, 0.f};
#pragma unroll
    for (int mt = 0; mt < 4; ++mt)
#pragma unroll
        for (int nt = 0; nt < 4; ++nt) acc[mt][nt] = zero;

    for (int k0 = 0; k0 < E_DIM; k0 += 32) {
#pragma unroll
        for (int i = 0; i < 2; ++i) {
            int c = i * 4 + w;                 // chunk 0..7 (16 rows x 64B)
            int row = c * 16 + rl;
            load_lds16(A + (size_t)(m0 + row) * E_DIM + k0 + gsw * 8, As + c * 512);
            load_lds16(W + (size_t)(n0 + row) * E_DIM + k0 + gsw * 8, Bs + c * 512);
        }
        __syncthreads();
        bf16x8 af[4], bfr[4];
#pragma unroll
        for (int mt = 0; mt < 4; ++mt)
            af[mt] = *(const bf16x8*)(As + (wm * 64 + mt * 16 + l16) * 32
                                      + ((quad ^ fsw) * 8));
#pragma unroll
        for (int nt = 0; nt < 4; ++nt)
            bfr[nt] = *(const bf16x8*)(Bs + (wn * 64 + nt * 16 + l16) * 32
                                       + ((quad ^ fsw) * 8));
#pragma unroll
        for (int mt = 0; mt < 4; ++mt)
#pragma unroll
            for (int nt = 0; nt < 4; ++nt)
                acc[mt][nt] = __builtin_amdgcn_mfma_f32_16x16x32_bf16(
                    af[mt], bfr[nt], acc[mt][nt], 0, 0, 0);
        __syncthreads();
    }
}

// ---------------------------------------------------------------------------
// QKV GEMM (z-grid) with fused epilogues:
//  z=0: K -> LN(kln) -> Kb
//  z=1: Q -> LN(qln) * 0.125*log2e -> Qb
//  z=2: V -> transposed store -> Vt [bh][d][t]
// ---------------------------------------------------------------------------
__global__ __launch_bounds__(256) void gemm_qkv(
    const ushort* __restrict__ A,
    const ushort* __restrict__ W0, const ushort* __restrict__ W1,
    const ushort* __restrict__ W2,
    ushort* __restrict__ Kb, ushort* __restrict__ Qb, ushort* __restrict__ Vt,
    const float* __restrict__ kw, const float* __restrict__ kbias,
    const float* __restrict__ qw, const float* __restrict__ qbias)
{
    __shared__ ushort As[128 * 32];
    __shared__ ushort Bs[128 * 32];
    const int z = blockIdx.z;
    const ushort* W = (z == 0) ? W0 : (z == 1) ? W1 : W2;
    const int m0 = blockIdx.y * 128, n0 = blockIdx.x * 128;
    f32x4 acc[4][4];
    gemm_core(A, W, m0, n0, As, Bs, acc);

    const int lane = threadIdx.x & 63, w = threadIdx.x >> 6;
    const int quad = lane >> 4, l16 = lane & 15;
    const int wm = w & 1, wn = w >> 1;
    const int row0 = m0 + wm * 64;
    const int col0 = n0 + wn * 64;

    if (z < 2) {
        ushort* C = z ? Qb : Kb;
        const float* lw = z ? qw : kw;
        const float* lb = z ? qbias : kbias;
        const float scale = z ? (0.125f * LOG2E) : 1.0f;
        float wv[4], bv_[4];
#pragma unroll
        for (int nt = 0; nt < 4; ++nt) {
            wv[nt]  = lw[nt * 16 + l16];
            bv_[nt] = lb[nt * 16 + l16];
        }
#pragma unroll
        for (int mt = 0; mt < 4; ++mt)
#pragma unroll
            for (int r = 0; r < 4; ++r) {
                float v[4], d[4];
#pragma unroll
                for (int nt = 0; nt < 4; ++nt) v[nt] = acc[mt][nt][r];
                float s = v[0] + v[1] + v[2] + v[3];
                s += __shfl_xor(s, 1); s += __shfl_xor(s, 2);
                s += __shfl_xor(s, 4); s += __shfl_xor(s, 8);
                float mu = s * (1.0f / 64.0f);
                float q2 = 0.f;
#pragma unroll
                for (int nt = 0; nt < 4; ++nt) { d[nt] = v[nt] - mu; q2 += d[nt] * d[nt]; }
                q2 += __shfl_xor(q2, 1); q2 += __shfl_xor(q2, 2);
                q2 += __shfl_xor(q2, 4); q2 += __shfl_xor(q2, 8);
                float rin = rsqrtf(q2 * (1.0f / 64.0f) + 1e-5f);
                int row = row0 + mt * 16 + quad * 4 + r;
#pragma unroll
                for (int nt = 0; nt < 4; ++nt)
                    C[(size_t)row * E_DIM + col0 + nt * 16 + l16] =
                        f2bf((d[nt] * rin * wv[nt] + bv_[nt]) * scale);
            }
    } else {
        // V: transposed store Vt[(b*NH+h)*64 + d][t]
        const int bidx = m0 >> 11;
        const int hh   = col0 >> 6;
        const int t0   = (m0 & 2047) + wm * 64;
#pragma unroll
        for (int mt = 0; mt < 4; ++mt)
#pragma unroll
            for (int nt = 0; nt < 4; ++nt) {
                ushort4 pk = make_ushort4(f2bf(acc[mt][nt][0]), f2bf(acc[mt][nt][1]),
                                          f2bf(acc[mt][nt][2]), f2bf(acc[mt][nt][3]));
                size_t off = ((size_t)(bidx * NH + hh) * 64 + nt * 16 + l16) * T_SEQ
                             + t0 + mt * 16 + quad * 4;
                *(ushort4*)(Vt + off) = pk;
            }
    }
}

// ---------------------------------------------------------------------------
// Output GEMM, 128(M)x64(N) tiles -> 512 blocks, 2x2 wave grid.
// ---------------------------------------------------------------------------
__global__ __launch_bounds__(256) void gemm_o(
    const ushort* __restrict__ A, const ushort* __restrict__ W,
    float* __restrict__ C)
{
    __shared__ ushort As[128 * 32];   // 8 KB
    __shared__ ushort Bs[64 * 32];    // 4 KB
    const int tid  = threadIdx.x;
    const int lane = tid & 63, w = tid >> 6;
    const int quad = lane >> 4, l16 = lane & 15;
    const int wm = w & 1, wn = w >> 1;
    const int m0 = blockIdx.y * 128, n0 = blockIdx.x * 64;

    const int rl  = lane >> 2;
    const int gsw = (lane & 3) ^ ((lane >> 3) & 3);
    const int fsw = (l16 >> 1) & 3;

    const f32x4 zero = {0.f, 0.f, 0.f, 0.f};
    f32x4 acc[4][2];
#pragma unroll
    for (int mt = 0; mt < 4; ++mt)
#pragma unroll
        for (int nt = 0; nt < 2; ++nt) acc[mt][nt] = zero;

    for (int k0 = 0; k0 < E_DIM; k0 += 32) {
#pragma unroll
        for (int i = 0; i < 2; ++i) {
            int c = i * 4 + w;
            int row = c * 16 + rl;
            load_lds16(A + (size_t)(m0 + row) * E_DIM + k0 + gsw * 8, As + c * 512);
        }
        {
            int row = w * 16 + rl;
            load_lds16(W + (size_t)(n0 + row) * E_DIM + k0 + gsw * 8, Bs + w * 512);
        }
        __syncthreads();
        bf16x8 af[4], bfr[2];
#pragma unroll
        for (int mt = 0; mt < 4; ++mt)
            af[mt] = *(const bf16x8*)(As + (wm * 64 + mt * 16 + l16) * 32
                                      + ((quad ^ fsw) * 8));
#pragma unroll
        for (int nt = 0; nt < 2; ++nt)
            bfr[nt] = *(const bf16x8*)(Bs + (wn * 32 + nt * 16 + l16) * 32
                                       + ((quad ^ fsw) * 8));
#pragma unroll
        for (int mt = 0; mt < 4; ++mt)
#pragma unroll
            for (int nt = 0; nt < 2; ++nt)
                acc[mt][nt] = __builtin_amdgcn_mfma_f32_16x16x32_bf16(
                    af[mt], bfr[nt], acc[mt][nt], 0, 0, 0);
        __syncthreads();
    }

    const int row0 = m0 + wm * 64;
    const int col0 = n0 + wn * 32;
#pragma unroll
    for (int mt = 0; mt < 4; ++mt)
#pragma unroll
        for (int nt = 0; nt < 2; ++nt)
#pragma unroll
            for (int r = 0; r < 4; ++r)
                C[(size_t)(row0 + mt * 16 + quad * 4 + r) * E_DIM
                  + col0 + nt * 16 + l16] = acc[mt][nt][r];
}

// ---------------------------------------------------------------------------
// Flash attention v5 (causal, bf16 MFMA, exp2 fixed-max softmax,
// REGISTER-DIRECT PV): compute S^T (A=K, B=Q) so the exp'd accumulator is
// already in the 16x16x16 B-operand layout (k=quad*4+j == C row quad*4+r);
// PV runs as O^T = V^T @ P^T with A=V^T straight from the transposed V tile.
// No P LDS round-trip. LDS = 32KB -> whole 1024-block grid resident (4/CU).
// ---------------------------------------------------------------------------
__global__ __launch_bounds__(256, 4) void flash_attn5(
    const ushort* __restrict__ Qg, const ushort* __restrict__ Kg,
    const ushort* __restrict__ Vt, ushort* __restrict__ O)
{
    __shared__ ushort Ks[2][64 * 64];   // 16 KB
    __shared__ ushort Vs[2][64 * 64];   // 16 KB

    const int tid  = threadIdx.x;
    const int lane = tid & 63, w = tid >> 6;
    const int quad = lane >> 4, l16 = lane & 15;

    // balance swizzle: class c gets qt in {q0, 15-q0, 16+q0, 31-q0} (sum 66)
    const int L = blockIdx.x;           // 0..1023
    const int c = L & 255, s = L >> 8;
    const int q0 = c >> 5;              // 0..7
    const int bh = c & 31;
    const int qt = (s == 0) ? q0 : (s == 1) ? (15 - q0)
                 : (s == 2) ? (16 + q0) : (31 - q0);
    const int b = bh >> 4, h = bh & 15;

    const ushort* Qbase = Qg + ((size_t)b * T_SEQ) * E_DIM + h * HS;
    const ushort* Kbase = Kg + ((size_t)b * T_SEQ) * E_DIM + h * HS;
    const ushort* Vbase = Vt + ((size_t)bh * HS) * T_SEQ;   // [d][t]

    const int rloc = lane >> 3;
    const int gswc = (lane & 7) ^ rloc;     // swizzled global chunk (staging)
    const int sw   = l16 & 7;               // frag-read xor factor

    // Q B-frags (16x16x32): B[n=q][k=d], lane n=l16 -> q row, k=quad*8+j
    bf16x8 aq[2];
#pragma unroll
    for (int ks = 0; ks < 2; ++ks)
        aq[ks] = *(const bf16x8*)(Qbase + (size_t)(qt * 64 + w * 16 + l16) * E_DIM
                                  + ks * 32 + quad * 8);

    const f32x4 zero = {0.f, 0.f, 0.f, 0.f};
    f32x4 o_acc[4];                     // O^T: lane col=q(l16), rows d=quad*4+r
#pragma unroll
    for (int dt = 0; dt < 4; ++dt) o_acc[dt] = zero;
    float l_acc = 0.f;                  // q is lane-fixed -> scalar l

    // initial stage into buffer 0
#pragma unroll
    for (int i = 0; i < 2; ++i) {
        int cc = w * 2 + i, row = cc * 8 + rloc;
        load_lds16(Kbase + (size_t)row * E_DIM + gswc * 8, Ks[0] + cc * 512);
        load_lds16(Vbase + (size_t)row * T_SEQ + gswc * 8, Vs[0] + cc * 512);
    }

    const float M8 = 8.0f * LOG2E;   // fixed max in exp2 domain

    for (int jt = 0; jt <= qt; ++jt) {
        const int buf = jt & 1;
        __syncthreads();   // drains vmcnt -> buf ready; syncs buffer reuse
        if (jt < qt) {
#pragma unroll
            for (int i = 0; i < 2; ++i) {
                int cc = w * 2 + i, row = cc * 8 + rloc;
                load_lds16(Kbase + (size_t)(jt + 1) * 64 * E_DIM
                           + (size_t)row * E_DIM + gswc * 8, Ks[buf ^ 1] + cc * 512);
                load_lds16(Vbase + (size_t)row * T_SEQ + (jt + 1) * 64 + gswc * 8,
                           Vs[buf ^ 1] + cc * 512);
            }
        }

        // S^T = K Q^T: tiles over t (nt). A=K-frag (m=t), B=aq (n=q).
        f32x4 sa[4];
#pragma unroll
        for (int nt = 0; nt < 4; ++nt) sa[nt] = zero;
#pragma unroll
        for (int ks = 0; ks < 2; ++ks) {
            int cp = ((ks * 4 + quad) ^ sw) * 8;
#pragma unroll
            for (int nt = 0; nt < 4; ++nt) {
                bf16x8 bk = *(const bf16x8*)(Ks[buf] + (nt * 16 + l16) * 64 + cp);
                sa[nt] = __builtin_amdgcn_mfma_f32_16x16x32_bf16(bk, aq[ks], sa[nt], 0, 0, 0);
            }
        }

        if (jt == qt) {   // causal mask: t > q  (tile-local coords, same origin)
#pragma unroll
            for (int nt = 0; nt < 4; ++nt)
#pragma unroll
                for (int r = 0; r < 4; ++r)
                    if (nt * 16 + quad * 4 + r > w * 16 + l16) sa[nt][r] = -1e30f;
        }

        // p = exp2(s - 8*log2e); scalar l accumulation; pack B-frags (trunc)
        bf16x4 bp[4];
#pragma unroll
        for (int nt = 0; nt < 4; ++nt)
#pragma unroll
            for (int r = 0; r < 4; ++r) {
                float p = __builtin_amdgcn_exp2f(sa[nt][r] - M8);
                l_acc += p;
                bp[nt][r] = (short)f2bf_trunc(p);
            }

        // O^T += V^T @ P^T : A = V^T rows d (from Vs), B = bp[kt] (k = t)
#pragma unroll
        for (int kt = 0; kt < 4; ++kt) {
            const int tt = kt * 16 + quad * 4;          // t of this k-slice
            const int ch = tt >> 3, el = tt & 7;
#pragma unroll
            for (int dt = 0; dt < 4; ++dt) {
                const int vd = dt * 16 + l16;
                bf16x4 va = *(const bf16x4*)(Vs[buf] + vd * 64
                                             + ((ch ^ (vd & 7)) << 3) + el);
                o_acc[dt] = mfma16(va, bp[kt], o_acc[dt]);
            }
        }
    }

    // Epilogue: l reduce across quads (q = l16 fixed), divide, pack, store.
    l_acc += __shfl_xor(l_acc, 16);
    l_acc += __shfl_xor(l_acc, 32);
    const float inv = 1.0f / l_acc;
    const int trow = qt * 64 + w * 16 + l16;
#pragma unroll
    for (int dt = 0; dt < 4; ++dt) {
        ushort4 pk = make_ushort4(f2bf(o_acc[dt][0] * inv), f2bf(o_acc[dt][1] * inv),
                                  f2bf(o_acc[dt][2] * inv), f2bf(o_acc[dt][3] * inv));
        *(ushort4*)(O + ((size_t)b * T_SEQ + trow) * E_DIM + h * HS
                    + dt * 16 + quad * 4) = pk;
    }
}

// ---------------------------------------------------------------------------
extern "C" void kernel_launch(void* const* d_in, const int* in_sizes, int n_in,
                              void* d_out, int out_size, void* d_ws, size_t ws_size,
                              hipStream_t stream) {
    const float* x     = (const float*)d_in[0];
    const float* Wk    = (const float*)d_in[1];
    const float* Wq    = (const float*)d_in[2];
    const float* Wv    = (const float*)d_in[3];
    const float* Wu    = (const float*)d_in[4];
    const float* kln_w = (const float*)d_in[5];
    const float* kln_b = (const float*)d_in[6];
    const float* qln_w = (const float*)d_in[7];
    const float* qln_b = (const float*)d_in[8];
    float* out = (float*)d_out;

    const size_t NE = (size_t)M_ROWS * E_DIM;   // 4M elems
    const size_t NW = (size_t)E_DIM * E_DIM;    // 1M elems
    ushort* xb  = (ushort*)d_ws;                // 4M
    ushort* Wkb = xb  + NE;                     // 1M each
    ushort* Wqb = Wkb + NW;
    ushort* Wvb = Wqb + NW;
    ushort* Wub = Wvb + NW;
    ushort* Kb  = Wub + NW;                     // 4M
    ushort* Qb  = Kb  + NE;                     // 4M
    ushort* Vt  = Qb  + NE;                     // 4M, [bh][d][t]
    ushort* Ob  = Vt  + NE;                     // 4M

    // 1) fp32 -> bf16
    cvt_all<<<8192, 256, 0, stream>>>(x, Wk, Wq, Wv, Wu, xb, Wkb, Wqb, Wvb, Wub);

    // 2) K/Q/V projections (128x128 z-grid) with fused LN + V-transpose
    gemm_qkv<<<dim3(E_DIM / 128, M_ROWS / 128, 3), 256, 0, stream>>>(
        xb, Wkb, Wqb, Wvb, Kb, Qb, Vt, kln_w, kln_b, qln_w, qln_b);

    // 3) Causal flash attention (register-direct PV, fully-resident grid)
    flash_attn5<<<1024, 256, 0, stream>>>(Qb, Kb, Vt, Ob);

    // 4) Output projection -> fp32 out
    gemm_o<<<dim3(E_DIM / 64, M_ROWS / 128), 256, 0, stream>>>(Ob, Wub, out);
}

// Round 10
// 181.544 us; speedup vs baseline: 1.1285x; 1.0017x over previous
//
#include <hip/hip_runtime.h>
#include <math.h>

// Problem constants (B=2, T=2048, E=1024, H=16, S=64)
#define T_SEQ 2048
#define E_DIM 1024
#define NH    16
#define HS    64
#define NB    2
#define M_ROWS 4096

typedef __attribute__((ext_vector_type(8))) short bf16x8;
typedef __attribute__((ext_vector_type(4))) short bf16x4;
typedef __attribute__((ext_vector_type(4))) float f32x4;

#define AS1 __attribute__((address_space(1)))
#define AS3 __attribute__((address_space(3)))

#define LOG2E 1.4426950408889634f

// 16x16x16 bf16 MFMA (K=16): B-operand k-index (quad*4+j) matches the
// C-layout row index (quad*4+r) — QK^T's S^T accumulator feeds PV directly.
__device__ __forceinline__ f32x4 mfma16(bf16x4 a, bf16x4 b, f32x4 c) {
    return __builtin_amdgcn_mfma_f32_16x16x16bf16_1k(a, b, c, 0, 0, 0);
}

__device__ __forceinline__ ushort f2bf(float f) {
    union { float f; unsigned u; } c; c.f = f;
    unsigned r = c.u + 0x7fffu + ((c.u >> 16) & 1u);
    return (ushort)(r >> 16);
}
__device__ __forceinline__ ushort f2bf_trunc(float f) {
    union { float f; unsigned u; } c; c.f = f;
    return (ushort)(c.u >> 16);
}

__device__ __forceinline__ void load_lds16(const ushort* g, ushort* l) {
    // 16B per lane, LDS dest = wave-uniform base + lane*16 (HW behavior)
    __builtin_amdgcn_global_load_lds((const AS1 unsigned int*)g,
                                     (AS3 unsigned int*)l, 16, 0, 0);
}

// ---------------------------------------------------------------------------
// fp32 -> bf16 conversion for x and the four weight matrices.
// ---------------------------------------------------------------------------
__global__ __launch_bounds__(256) void cvt_all(
    const float* __restrict__ x,  const float* __restrict__ Wk,
    const float* __restrict__ Wq, const float* __restrict__ Wv,
    const float* __restrict__ Wu,
    ushort* __restrict__ xb,  ushort* __restrict__ Wkb,
    ushort* __restrict__ Wqb, ushort* __restrict__ Wvb,
    ushort* __restrict__ Wub)
{
    int i4 = blockIdx.x * 256 + threadIdx.x;   // 0 .. 2M-1 (float4 units)
    int region = i4 >> 18;
    const float* src; ushort* dst; int off;
    if      (region < 4)  { src = x;  dst = xb;  off = i4; }
    else if (region == 4) { src = Wk; dst = Wkb; off = i4 - (4 << 18); }
    else if (region == 5) { src = Wq; dst = Wqb; off = i4 - (5 << 18); }
    else if (region == 6) { src = Wv; dst = Wvb; off = i4 - (6 << 18); }
    else                  { src = Wu; dst = Wub; off = i4 - (7 << 18); }
    float4 v = *(const float4*)(src + (size_t)off * 4);
    ushort4 o; o.x = f2bf(v.x); o.y = f2bf(v.y); o.z = f2bf(v.z); o.w = f2bf(v.w);
    *(ushort4*)(dst + (size_t)off * 4) = o;
}

// ---------------------------------------------------------------------------
// bf16 MFMA GEMM core with DOUBLE-BUFFERED staging and ONE barrier per
// K-iteration (flash5 pattern): prefetch k+32 right after the barrier, then
// compute k. Each wave's vmcnt drains at the NEXT barrier, so a full
// MFMA+ds_read stage overlaps the global->LDS loads. This is the fix for the
// 1-3 blocks/CU regime where implicit multi-block overlap can't hide drains.
// 128x128 tile, BK=32, 4 waves in 2x2, 16 MFMA/wave/iter. LDS 32KB.
// ---------------------------------------------------------------------------
__device__ __forceinline__ void gemm_core_db(
    const ushort* __restrict__ A, const ushort* __restrict__ W,
    int m0, int n0, ushort* As, ushort* Bs, f32x4 acc[4][4])
{
    const int tid  = threadIdx.x;
    const int lane = tid & 63, w = tid >> 6;
    const int quad = lane >> 4, l16 = lane & 15;
    const int wm = w & 1, wn = w >> 1;

    const int rl   = lane >> 2;                       // row-in-chunk 0..15
    const int gsw  = (lane & 3) ^ ((lane >> 3) & 3);  // swizzled global chunk
    const int fsw  = (l16 >> 1) & 3;                  // frag-read xor factor

    const f32x4 zero = {0.f, 0.f, 0.f, 0.f};
#pragma unroll
    for (int mt = 0; mt < 4; ++mt)
#pragma unroll
        for (int nt = 0; nt < 4; ++nt) acc[mt][nt] = zero;

    // initial stage into buffer 0
#pragma unroll
    for (int i = 0; i < 2; ++i) {
        int c = i * 4 + w;                 // chunk 0..7 (16 rows x 64B)
        int row = c * 16 + rl;
        load_lds16(A + (size_t)(m0 + row) * E_DIM + gsw * 8, As + c * 512);
        load_lds16(W + (size_t)(n0 + row) * E_DIM + gsw * 8, Bs + c * 512);
    }

    for (int k0 = 0; k0 < E_DIM; k0 += 32) {
        const int buf = (k0 >> 5) & 1;
        ushort* Ab = As + buf * 4096;
        ushort* Bb = Bs + buf * 4096;
        __syncthreads();   // own-wave vmcnt drained -> buf ready; syncs reuse
        if (k0 + 32 < E_DIM) {
            ushort* An = As + (buf ^ 1) * 4096;
            ushort* Bn = Bs + (buf ^ 1) * 4096;
#pragma unroll
            for (int i = 0; i < 2; ++i) {
                int c = i * 4 + w;
                int row = c * 16 + rl;
                load_lds16(A + (size_t)(m0 + row) * E_DIM + k0 + 32 + gsw * 8,
                           An + c * 512);
                load_lds16(W + (size_t)(n0 + row) * E_DIM + k0 + 32 + gsw * 8,
                           Bn + c * 512);
            }
        }
        bf16x8 af[4], bfr[4];
#pragma unroll
        for (int mt = 0; mt < 4; ++mt)
            af[mt] = *(const bf16x8*)(Ab + (wm * 64 + mt * 16 + l16) * 32
                                      + ((quad ^ fsw) * 8));
#pragma unroll
        for (int nt = 0; nt < 4; ++nt)
            bfr[nt] = *(const bf16x8*)(Bb + (wn * 64 + nt * 16 + l16) * 32
                                       + ((quad ^ fsw) * 8));
#pragma unroll
        for (int mt = 0; mt < 4; ++mt)
#pragma unroll
            for (int nt = 0; nt < 4; ++nt)
                acc[mt][nt] = __builtin_amdgcn_mfma_f32_16x16x32_bf16(
                    af[mt], bfr[nt], acc[mt][nt], 0, 0, 0);
    }
}

// ---------------------------------------------------------------------------
// QKV GEMM (z-grid) with fused epilogues:
//  z=0: K -> LN(kln) -> Kb
//  z=1: Q -> LN(qln) * 0.125*log2e -> Qb
//  z=2: V -> transposed store -> Vt [bh][d][t]
// ---------------------------------------------------------------------------
__global__ __launch_bounds__(256) void gemm_qkv(
    const ushort* __restrict__ A,
    const ushort* __restrict__ W0, const ushort* __restrict__ W1,
    const ushort* __restrict__ W2,
    ushort* __restrict__ Kb, ushort* __restrict__ Qb, ushort* __restrict__ Vt,
    const float* __restrict__ kw, const float* __restrict__ kbias,
    const float* __restrict__ qw, const float* __restrict__ qbias)
{
    __shared__ ushort As[2 * 128 * 32];   // 16 KB
    __shared__ ushort Bs[2 * 128 * 32];   // 16 KB
    const int z = blockIdx.z;
    const ushort* W = (z == 0) ? W0 : (z == 1) ? W1 : W2;
    const int m0 = blockIdx.y * 128, n0 = blockIdx.x * 128;
    f32x4 acc[4][4];
    gemm_core_db(A, W, m0, n0, As, Bs, acc);

    const int lane = threadIdx.x & 63, w = threadIdx.x >> 6;
    const int quad = lane >> 4, l16 = lane & 15;
    const int wm = w & 1, wn = w >> 1;
    const int row0 = m0 + wm * 64;
    const int col0 = n0 + wn * 64;

    if (z < 2) {
        ushort* C = z ? Qb : Kb;
        const float* lw = z ? qw : kw;
        const float* lb = z ? qbias : kbias;
        const float scale = z ? (0.125f * LOG2E) : 1.0f;
        float wv[4], bv_[4];
#pragma unroll
        for (int nt = 0; nt < 4; ++nt) {
            wv[nt]  = lw[nt * 16 + l16];
            bv_[nt] = lb[nt * 16 + l16];
        }
#pragma unroll
        for (int mt = 0; mt < 4; ++mt)
#pragma unroll
            for (int r = 0; r < 4; ++r) {
                float v[4], d[4];
#pragma unroll
                for (int nt = 0; nt < 4; ++nt) v[nt] = acc[mt][nt][r];
                float s = v[0] + v[1] + v[2] + v[3];
                s += __shfl_xor(s, 1); s += __shfl_xor(s, 2);
                s += __shfl_xor(s, 4); s += __shfl_xor(s, 8);
                float mu = s * (1.0f / 64.0f);
                float q2 = 0.f;
#pragma unroll
                for (int nt = 0; nt < 4; ++nt) { d[nt] = v[nt] - mu; q2 += d[nt] * d[nt]; }
                q2 += __shfl_xor(q2, 1); q2 += __shfl_xor(q2, 2);
                q2 += __shfl_xor(q2, 4); q2 += __shfl_xor(q2, 8);
                float rin = rsqrtf(q2 * (1.0f / 64.0f) + 1e-5f);
                int row = row0 + mt * 16 + quad * 4 + r;
#pragma unroll
                for (int nt = 0; nt < 4; ++nt)
                    C[(size_t)row * E_DIM + col0 + nt * 16 + l16] =
                        f2bf((d[nt] * rin * wv[nt] + bv_[nt]) * scale);
            }
    } else {
        // V: transposed store Vt[(b*NH+h)*64 + d][t]
        const int bidx = m0 >> 11;
        const int hh   = col0 >> 6;
        const int t0   = (m0 & 2047) + wm * 64;
#pragma unroll
        for (int mt = 0; mt < 4; ++mt)
#pragma unroll
            for (int nt = 0; nt < 4; ++nt) {
                ushort4 pk = make_ushort4(f2bf(acc[mt][nt][0]), f2bf(acc[mt][nt][1]),
                                          f2bf(acc[mt][nt][2]), f2bf(acc[mt][nt][3]));
                size_t off = ((size_t)(bidx * NH + hh) * 64 + nt * 16 + l16) * T_SEQ
                             + t0 + mt * 16 + quad * 4;
                *(ushort4*)(Vt + off) = pk;
            }
    }
}

// ---------------------------------------------------------------------------
// Output GEMM: 128x128 tiles (grid 8x32 = 256 blocks), dbuf core, fp32 store.
// ---------------------------------------------------------------------------
__global__ __launch_bounds__(256) void gemm_o(
    const ushort* __restrict__ A, const ushort* __restrict__ W,
    float* __restrict__ C)
{
    __shared__ ushort As[2 * 128 * 32];
    __shared__ ushort Bs[2 * 128 * 32];
    const int m0 = blockIdx.y * 128, n0 = blockIdx.x * 128;
    f32x4 acc[4][4];
    gemm_core_db(A, W, m0, n0, As, Bs, acc);

    const int lane = threadIdx.x & 63, w = threadIdx.x >> 6;
    const int quad = lane >> 4, l16 = lane & 15;
    const int row0 = m0 + (w & 1) * 64;
    const int col0 = n0 + (w >> 1) * 64;
#pragma unroll
    for (int mt = 0; mt < 4; ++mt)
#pragma unroll
        for (int nt = 0; nt < 4; ++nt)
#pragma unroll
            for (int r = 0; r < 4; ++r)
                C[(size_t)(row0 + mt * 16 + quad * 4 + r) * E_DIM
                  + col0 + nt * 16 + l16] = acc[mt][nt][r];
}

// ---------------------------------------------------------------------------
// Flash attention v5 (causal, bf16 MFMA, exp2 fixed-max softmax,
// register-direct PV via S^T). Unchanged from round 9 (42 µs).
// ---------------------------------------------------------------------------
__global__ __launch_bounds__(256, 4) void flash_attn5(
    const ushort* __restrict__ Qg, const ushort* __restrict__ Kg,
    const ushort* __restrict__ Vt, ushort* __restrict__ O)
{
    __shared__ ushort Ks[2][64 * 64];   // 16 KB
    __shared__ ushort Vs[2][64 * 64];   // 16 KB

    const int tid  = threadIdx.x;
    const int lane = tid & 63, w = tid >> 6;
    const int quad = lane >> 4, l16 = lane & 15;

    // balance swizzle: class c gets qt in {q0, 15-q0, 16+q0, 31-q0} (sum 66)
    const int L = blockIdx.x;           // 0..1023
    const int c = L & 255, s = L >> 8;
    const int q0 = c >> 5;              // 0..7
    const int bh = c & 31;
    const int qt = (s == 0) ? q0 : (s == 1) ? (15 - q0)
                 : (s == 2) ? (16 + q0) : (31 - q0);
    const int b = bh >> 4, h = bh & 15;

    const ushort* Qbase = Qg + ((size_t)b * T_SEQ) * E_DIM + h * HS;
    const ushort* Kbase = Kg + ((size_t)b * T_SEQ) * E_DIM + h * HS;
    const ushort* Vbase = Vt + ((size_t)bh * HS) * T_SEQ;   // [d][t]

    const int rloc = lane >> 3;
    const int gswc = (lane & 7) ^ rloc;     // swizzled global chunk (staging)
    const int sw   = l16 & 7;               // frag-read xor factor

    // Q B-frags (16x16x32): B[n=q][k=d], lane n=l16 -> q row, k=quad*8+j
    bf16x8 aq[2];
#pragma unroll
    for (int ks = 0; ks < 2; ++ks)
        aq[ks] = *(const bf16x8*)(Qbase + (size_t)(qt * 64 + w * 16 + l16) * E_DIM
                                  + ks * 32 + quad * 8);

    const f32x4 zero = {0.f, 0.f, 0.f, 0.f};
    f32x4 o_acc[4];                     // O^T: lane col=q(l16), rows d=quad*4+r
#pragma unroll
    for (int dt = 0; dt < 4; ++dt) o_acc[dt] = zero;
    float l_acc = 0.f;                  // q is lane-fixed -> scalar l

    // initial stage into buffer 0
#pragma unroll
    for (int i = 0; i < 2; ++i) {
        int cc = w * 2 + i, row = cc * 8 + rloc;
        load_lds16(Kbase + (size_t)row * E_DIM + gswc * 8, Ks[0] + cc * 512);
        load_lds16(Vbase + (size_t)row * T_SEQ + gswc * 8, Vs[0] + cc * 512);
    }

    const float M8 = 8.0f * LOG2E;   // fixed max in exp2 domain

    for (int jt = 0; jt <= qt; ++jt) {
        const int buf = jt & 1;
        __syncthreads();   // drains vmcnt -> buf ready; syncs buffer reuse
        if (jt < qt) {
#pragma unroll
            for (int i = 0; i < 2; ++i) {
                int cc = w * 2 + i, row = cc * 8 + rloc;
                load_lds16(Kbase + (size_t)(jt + 1) * 64 * E_DIM
                           + (size_t)row * E_DIM + gswc * 8, Ks[buf ^ 1] + cc * 512);
                load_lds16(Vbase + (size_t)row * T_SEQ + (jt + 1) * 64 + gswc * 8,
                           Vs[buf ^ 1] + cc * 512);
            }
        }

        // S^T = K Q^T: tiles over t (nt). A=K-frag (m=t), B=aq (n=q).
        f32x4 sa[4];
#pragma unroll
        for (int nt = 0; nt < 4; ++nt) sa[nt] = zero;
#pragma unroll
        for (int ks = 0; ks < 2; ++ks) {
            int cp = ((ks * 4 + quad) ^ sw) * 8;
#pragma unroll
            for (int nt = 0; nt < 4; ++nt) {
                bf16x8 bk = *(const bf16x8*)(Ks[buf] + (nt * 16 + l16) * 64 + cp);
                sa[nt] = __builtin_amdgcn_mfma_f32_16x16x32_bf16(bk, aq[ks], sa[nt], 0, 0, 0);
            }
        }

        if (jt == qt) {   // causal mask: t > q  (tile-local coords, same origin)
#pragma unroll
            for (int nt = 0; nt < 4; ++nt)
#pragma unroll
                for (int r = 0; r < 4; ++r)
                    if (nt * 16 + quad * 4 + r > w * 16 + l16) sa[nt][r] = -1e30f;
        }

        // p = exp2(s - 8*log2e); scalar l accumulation; pack B-frags (trunc)
        bf16x4 bp[4];
#pragma unroll
        for (int nt = 0; nt < 4; ++nt)
#pragma unroll
            for (int r = 0; r < 4; ++r) {
                float p = __builtin_amdgcn_exp2f(sa[nt][r] - M8);
                l_acc += p;
                bp[nt][r] = (short)f2bf_trunc(p);
            }

        // O^T += V^T @ P^T : A = V^T rows d (from Vs), B = bp[kt] (k = t)
#pragma unroll
        for (int kt = 0; kt < 4; ++kt) {
            const int tt = kt * 16 + quad * 4;          // t of this k-slice
            const int ch = tt >> 3, el = tt & 7;
#pragma unroll
            for (int dt = 0; dt < 4; ++dt) {
                const int vd = dt * 16 + l16;
                bf16x4 va = *(const bf16x4*)(Vs[buf] + vd * 64
                                             + ((ch ^ (vd & 7)) << 3) + el);
                o_acc[dt] = mfma16(va, bp[kt], o_acc[dt]);
            }
        }
    }

    // Epilogue: l reduce across quads (q = l16 fixed), divide, pack, store.
    l_acc += __shfl_xor(l_acc, 16);
    l_acc += __shfl_xor(l_acc, 32);
    const float inv = 1.0f / l_acc;
    const int trow = qt * 64 + w * 16 + l16;
#pragma unroll
    for (int dt = 0; dt < 4; ++dt) {
        ushort4 pk = make_ushort4(f2bf(o_acc[dt][0] * inv), f2bf(o_acc[dt][1] * inv),
                                  f2bf(o_acc[dt][2] * inv), f2bf(o_acc[dt][3] * inv));
        *(ushort4*)(O + ((size_t)b * T_SEQ + trow) * E_DIM + h * HS
                    + dt * 16 + quad * 4) = pk;
    }
}

// ---------------------------------------------------------------------------
extern "C" void kernel_launch(void* const* d_in, const int* in_sizes, int n_in,
                              void* d_out, int out_size, void* d_ws, size_t ws_size,
                              hipStream_t stream) {
    const float* x     = (const float*)d_in[0];
    const float* Wk    = (const float*)d_in[1];
    const float* Wq    = (const float*)d_in[2];
    const float* Wv    = (const float*)d_in[3];
    const float* Wu    = (const float*)d_in[4];
    const float* kln_w = (const float*)d_in[5];
    const float* kln_b = (const float*)d_in[6];
    const float* qln_w = (const float*)d_in[7];
    const float* qln_b = (const float*)d_in[8];
    float* out = (float*)d_out;

    const size_t NE = (size_t)M_ROWS * E_DIM;   // 4M elems
    const size_t NW = (size_t)E_DIM * E_DIM;    // 1M elems
    ushort* xb  = (ushort*)d_ws;                // 4M
    ushort* Wkb = xb  + NE;                     // 1M each
    ushort* Wqb = Wkb + NW;
    ushort* Wvb = Wqb + NW;
    ushort* Wub = Wvb + NW;
    ushort* Kb  = Wub + NW;                     // 4M
    ushort* Qb  = Kb  + NE;                     // 4M
    ushort* Vt  = Qb  + NE;                     // 4M, [bh][d][t]
    ushort* Ob  = Vt  + NE;                     // 4M

    // 1) fp32 -> bf16
    cvt_all<<<8192, 256, 0, stream>>>(x, Wk, Wq, Wv, Wu, xb, Wkb, Wqb, Wvb, Wub);

    // 2) K/Q/V projections (128x128 z-grid, dbuf) with fused LN + V-transpose
    gemm_qkv<<<dim3(E_DIM / 128, M_ROWS / 128, 3), 256, 0, stream>>>(
        xb, Wkb, Wqb, Wvb, Kb, Qb, Vt, kln_w, kln_b, qln_w, qln_b);

    // 3) Causal flash attention (register-direct PV)
    flash_attn5<<<1024, 256, 0, stream>>>(Qb, Kb, Vt, Ob);

    // 4) Output projection (128x128, dbuf) -> fp32 out
    gemm_o<<<dim3(E_DIM / 128, M_ROWS / 128), 256, 0, stream>>>(Ob, Wub, out);
}